// Round 5
// baseline (725.590 us; speedup 1.0000x reference)
//
#include <hip/hip_runtime.h>
#include <stdint.h>

#define NG 256      // num networks
#define KF 256      // IN_F
#define OF 256      // OUT_F
#define BM 128      // rows per tile
#define BK 32       // k-chunk
#define NKT 8       // KF / BK
#define NTILES 16   // PAD / BM
#define NTH 512     // 8 waves

using f32x4  = __attribute__((ext_vector_type(4))) float;
using bf16x8 = __attribute__((ext_vector_type(8))) __bf16;
using u16x8  = __attribute__((ext_vector_type(8))) unsigned short;

__device__ __forceinline__ unsigned short f2bf(float f) {
  unsigned u = __builtin_bit_cast(unsigned, f);
  u += 0x7fffu + ((u >> 16) & 1u);   // round-to-nearest-even
  return (unsigned short)(u >> 16);
}

// ---------------- offsets scan (1 block, 256 threads) ----------------
__global__ void scan_kernel(const int* __restrict__ counts, int* __restrict__ offs) {
  __shared__ int s[NG];
  int t = threadIdx.x;
  s[t] = counts[t];
  __syncthreads();
  #pragma unroll
  for (int d = 1; d < NG; d <<= 1) {
    int u = (t >= d) ? s[t - d] : 0;
    __syncthreads();
    s[t] += u;
    __syncthreads();
  }
  if (t == 0) offs[0] = 0;
  offs[t + 1] = s[t];
}

// ---------------- W f32 -> bf16 pre-swizzled image ----------------
// slot16 index = ((g*8+kt)*256 + o)*4 + s'   (16 B each)
// holds W[g][o][kt*32 + (s'^((o>>1)&3))*8 .. +8] as bf16x8.
// Linear global_load_lds then reproduces the swizzled LDS tile:
// LDS ushort idx (o*4+s')*8, conflict-free for the frag read pattern.
__global__ __launch_bounds__(512)
void wconv_kernel(const float* __restrict__ w, unsigned short* __restrict__ img) {
  int tid = blockIdx.x * 512 + threadIdx.x;   // one 16B slot each, 2^21 total
  int sp = tid & 3;
  int o  = (tid >> 2) & 255;
  int kt = (tid >> 10) & 7;
  int g  = tid >> 13;
  int s  = sp ^ ((o >> 1) & 3);
  int k0 = kt * 32 + s * 8;
  const float* src = w + ((size_t)(g * 256 + o) * 256 + k0);
  f32x4 a = *(const f32x4*)src;
  f32x4 b = *(const f32x4*)(src + 4);
  u16x8 r;
  r[0]=f2bf(a[0]); r[1]=f2bf(a[1]); r[2]=f2bf(a[2]); r[3]=f2bf(a[3]);
  r[4]=f2bf(b[0]); r[5]=f2bf(b[1]); r[6]=f2bf(b[2]); r[7]=f2bf(b[3]);
  *(u16x8*)(img + (size_t)tid * 8) = r;
}

// ---------------- grouped GEMM ----------------
// Block: 128 rows x 256 cols. 8 waves as 2M x 4N; wave = 64 rows x 64 cols.
// A (x rows): global->reg f32, cvt to bf16 frags. B (W): LDS, 3-buf pipeline.
template<bool PRECONV>
__global__ __launch_bounds__(NTH, 4)
void gemm_kernel(const float* __restrict__ x,
                 const float* __restrict__ wf32,
                 const unsigned short* __restrict__ wimg,
                 const float* __restrict__ bias,
                 const int* __restrict__ offs,
                 float* __restrict__ out)
{
  __shared__ __align__(16) unsigned short Bs[3][OF * BK];  // 3 x 16KB

  const int g      = blockIdx.y;
  const int r0     = offs[g];
  const int cnt    = offs[g + 1] - r0;
  const int tstart = blockIdx.x * BM;
  if (tstart >= cnt) return;
  const int mrows = min(BM, cnt - tstart);
  const int row0  = r0 + tstart;

  const int tid  = threadIdx.x;
  const int lane = tid & 63;
  const int wid  = tid >> 6;
  const int wm   = wid >> 2;      // 0..1 : M
  const int wn   = wid & 3;       // 0..3 : N
  const int lrow = lane & 15;
  const int lk   = lane >> 4;     // 0..3
  const int slot = lk ^ ((lrow >> 1) & 3);   // conflict-free swizzle slot

  // A addressing: uniform base + per-lane 32-bit element offsets (4 m-frags)
  const float* abase = x + (size_t)row0 * KF;
  int aoff[4];
  #pragma unroll
  for (int m = 0; m < 4; ++m) {
    int r = min(wm * 64 + m * 16 + lrow, mrows - 1);   // clamp: OOB rows dup, stores guarded
    aoff[m] = r * KF + lk * 8;
  }

  f32x4 areg[4][2];
  auto issueA = [&](int kt) {
    #pragma unroll
    for (int m = 0; m < 4; ++m) {
      const float* p = abase + aoff[m] + kt * BK;
      areg[m][0] = *(const f32x4*)(p);
      areg[m][1] = *(const f32x4*)(p + 4);
    }
  };

  auto issueB = [&](int kt, int buf) {
    const unsigned short* sb = wimg + (((size_t)(g * 8 + kt)) << 13);  // 8192 ushorts
    #pragma unroll
    for (int r = 0; r < 2; ++r) {
      int c = wid * 2 + r;                           // 16 x 1KB chunks
      __builtin_amdgcn_global_load_lds(
          (const __attribute__((address_space(1))) void*)(sb + c * 512 + lane * 8),
          (__attribute__((address_space(3))) void*)((char*)&Bs[buf][0] + c * 1024),
          16, 0, 0);
    }
  };

  // acc[n][m]: o = wn*64 + n*16 + lk*4 + j ; xrow = wm*64 + m*16 + lrow
  // init with bias (broadcast over rows)
  f32x4 acc[4][4];
  #pragma unroll
  for (int n = 0; n < 4; ++n) {
    f32x4 b4 = *(const f32x4*)&bias[g * OF + wn * 64 + n * 16 + lk * 4];
    #pragma unroll
    for (int m = 0; m < 4; ++m) acc[n][m] = b4;
  }

  auto cvtA = [&](int m) -> bf16x8 {
    f32x4 lo = areg[m][0], hi = areg[m][1];
    u16x8 r;
    r[0]=f2bf(lo[0]); r[1]=f2bf(lo[1]); r[2]=f2bf(lo[2]); r[3]=f2bf(lo[3]);
    r[4]=f2bf(hi[0]); r[5]=f2bf(hi[1]); r[6]=f2bf(hi[2]); r[7]=f2bf(hi[3]);
    return __builtin_bit_cast(bf16x8, r);
  };

  auto compute = [&](const bf16x8* xf, int buf) {
    #pragma unroll
    for (int n = 0; n < 4; ++n) {
      int o16 = (wn * 64 + n * 16 + lrow) * 32 + slot * 8;
      bf16x8 wf = *(const bf16x8*)&Bs[buf][o16];
      #pragma unroll
      for (int m = 0; m < 4; ++m)
        acc[n][m] = __builtin_amdgcn_mfma_f32_16x16x32_bf16(wf, xf[m], acc[n][m], 0, 0, 0);
    }
  };

  if (PRECONV) {
    // Prologue order matters: B(0) must be OLDEST so the kt=0 vmcnt(10)
    // (and the compiler's wait for A(0) at cvtA) both guarantee B(0) landed.
    // FIFO: B(0):2, A(0):8, B(1):2  -> vmcnt(10) drains exactly B(0).
    issueB(0, 0);
    issueA(0);
    issueB(1, 1);
    #pragma unroll
    for (int kt = 0; kt < NKT; ++kt) {
      // Steady state at top of iter kt: in flight = B(kt+1):2, A(kt):8;
      // B(kt) already drained by previous iter's A-wait (per wave, pre-barrier).
      if (kt + 1 < NKT) asm volatile("s_waitcnt vmcnt(10)" ::: "memory");
      else              asm volatile("s_waitcnt vmcnt(8)"  ::: "memory");
      __builtin_amdgcn_s_barrier();
      __builtin_amdgcn_sched_barrier(0);
      if (kt + 2 < NKT) issueB(kt + 2, (kt + 2) % 3);
      bf16x8 xf[4];
      #pragma unroll
      for (int m = 0; m < 4; ++m) xf[m] = cvtA(m);   // compiler waits A(kt) here
      if (kt + 1 < NKT) issueA(kt + 1);              // refill freed f32 regs
      __builtin_amdgcn_sched_barrier(0);
      compute(xf, kt % 3);
    }
  } else {
    // fallback: stage B from f32 weights each kt, single buffer
    #pragma unroll
    for (int kt = 0; kt < NKT; ++kt) {
      u16x8 v[2];
      #pragma unroll
      for (int r = 0; r < 2; ++r) {
        int sl = tid * 2 + r;          // slot16 index = o*4 + s'
        int o = sl >> 2, sp = sl & 3;
        int s = sp ^ ((o >> 1) & 3);
        const float* src = wf32 + ((size_t)(g * 256 + o) * 256 + kt * 32 + s * 8);
        f32x4 a = *(const f32x4*)src;
        f32x4 b = *(const f32x4*)(src + 4);
        v[r][0]=f2bf(a[0]); v[r][1]=f2bf(a[1]); v[r][2]=f2bf(a[2]); v[r][3]=f2bf(a[3]);
        v[r][4]=f2bf(b[0]); v[r][5]=f2bf(b[1]); v[r][6]=f2bf(b[2]); v[r][7]=f2bf(b[3]);
      }
      __syncthreads();   // previous compute done reading Bs[0]
      #pragma unroll
      for (int r = 0; r < 2; ++r)
        *(u16x8*)&Bs[0][(tid * 2 + r) * 8] = v[r];
      __syncthreads();
      issueA(kt);
      bf16x8 xf[4];
      #pragma unroll
      for (int m = 0; m < 4; ++m) xf[m] = cvtA(m);
      compute(xf, 0);
    }
  }

  // epilogue: pure f32x4 stores (bias already in acc)
  #pragma unroll
  for (int m = 0; m < 4; ++m) {
    int r = wm * 64 + m * 16 + lrow;
    if (r < mrows) {
      float* orow = out + (size_t)(row0 + r) * OF + wn * 64 + lk * 4;
      #pragma unroll
      for (int n = 0; n < 4; ++n)
        *(f32x4*)&orow[n * 16] = acc[n][m];
    }
  }
}

extern "C" void kernel_launch(void* const* d_in, const int* in_sizes, int n_in,
                              void* d_out, int out_size, void* d_ws, size_t ws_size,
                              hipStream_t stream) {
  const float* weight = (const float*)d_in[0];
  const float* bias   = (const float*)d_in[1];
  const float* x      = (const float*)d_in[2];
  const int*   counts = (const int*)d_in[3];
  float* out = (float*)d_out;

  int* offs = (int*)d_ws;
  unsigned short* wimg = (unsigned short*)((char*)d_ws + 4096);
  const size_t need = 4096 + (size_t)NG * 8 * 16384;  // ~32 MB image

  scan_kernel<<<1, 256, 0, stream>>>(counts, offs);

  if (ws_size >= need) {
    wconv_kernel<<<(NG * 8 * 256 * 4) / 512, 512, 0, stream>>>(weight, wimg);
    gemm_kernel<true><<<dim3(NTILES, NG), NTH, 0, stream>>>(x, weight, wimg, bias, offs, out);
  } else {
    gemm_kernel<false><<<dim3(NTILES, NG), NTH, 0, stream>>>(x, weight, wimg, bias, offs, out);
  }
}

// Round 6
// 387.472 us; speedup vs baseline: 1.8726x; 1.8726x over previous
//
#include <hip/hip_runtime.h>
#include <stdint.h>

#define NG 256      // num networks
#define KF 256      // IN_F
#define OF 256      // OUT_F
#define BM 128      // rows per tile
#define BK 32       // k-chunk
#define NKT 8       // KF / BK
#define NTILES 16   // PAD / BM
#define NTH 512     // 8 waves

using f32x4  = __attribute__((ext_vector_type(4))) float;
using bf16x8 = __attribute__((ext_vector_type(8))) __bf16;
using u16x8  = __attribute__((ext_vector_type(8))) unsigned short;

__device__ __forceinline__ unsigned short f2bf(float f) {
  unsigned u = __builtin_bit_cast(unsigned, f);
  u += 0x7fffu + ((u >> 16) & 1u);   // round-to-nearest-even
  return (unsigned short)(u >> 16);
}

// ---------------- offsets scan (1 block, 256 threads) ----------------
__global__ void scan_kernel(const int* __restrict__ counts, int* __restrict__ offs) {
  __shared__ int s[NG];
  int t = threadIdx.x;
  s[t] = counts[t];
  __syncthreads();
  #pragma unroll
  for (int d = 1; d < NG; d <<= 1) {
    int u = (t >= d) ? s[t - d] : 0;
    __syncthreads();
    s[t] += u;
    __syncthreads();
  }
  if (t == 0) offs[0] = 0;
  offs[t + 1] = s[t];
}

// ---------------- W f32 -> bf16 pre-swizzled image ----------------
// slot16 index = ((g*8+kt)*256 + o)*4 + s'   (16 B each)
// holds W[g][o][kt*32 + (s'^((o>>1)&3))*8 .. +8] as bf16x8.
// Linear global_load_lds reproduces the swizzled LDS tile.
__global__ __launch_bounds__(512)
void wconv_kernel(const float* __restrict__ w, unsigned short* __restrict__ img) {
  int tid = blockIdx.x * 512 + threadIdx.x;   // one 16B slot each, 2^21 total
  int sp = tid & 3;
  int o  = (tid >> 2) & 255;
  int kt = (tid >> 10) & 7;
  int g  = tid >> 13;
  int s  = sp ^ ((o >> 1) & 3);
  int k0 = kt * 32 + s * 8;
  const float* src = w + ((size_t)(g * 256 + o) * 256 + k0);
  f32x4 a = *(const f32x4*)src;
  f32x4 b = *(const f32x4*)(src + 4);
  u16x8 r;
  r[0]=f2bf(a[0]); r[1]=f2bf(a[1]); r[2]=f2bf(a[2]); r[3]=f2bf(a[3]);
  r[4]=f2bf(b[0]); r[5]=f2bf(b[1]); r[6]=f2bf(b[2]); r[7]=f2bf(b[3]);
  *(u16x8*)(img + (size_t)tid * 8) = r;
}

// ---------------- grouped GEMM ----------------
// Block: 128 rows x 256 cols. 8 waves as 2M x 4N; wave = 64 rows x 64 cols.
// A: global->reg f32 (2-deep prefetch), cvt bf16 at use. B: LDS 3-buf pipeline.
// __launch_bounds__(512,2): 256-reg cap -> NO SPILLS (R5 lesson: cap 128
// forced ~14-reg spill = +800MB scratch writes, 3.3x slowdown).
template<bool PRECONV>
__global__ __launch_bounds__(NTH, 2)
void gemm_kernel(const float* __restrict__ x,
                 const float* __restrict__ wf32,
                 const unsigned short* __restrict__ wimg,
                 const float* __restrict__ bias,
                 const int* __restrict__ offs,
                 float* __restrict__ out)
{
  __shared__ __align__(16) unsigned short Bs[3][OF * BK];  // 3 x 16KB

  const int g      = blockIdx.y;
  const int r0     = offs[g];
  const int cnt    = offs[g + 1] - r0;
  const int tstart = blockIdx.x * BM;
  if (tstart >= cnt) return;
  const int mrows = min(BM, cnt - tstart);
  const int row0  = r0 + tstart;

  const int tid  = threadIdx.x;
  const int lane = tid & 63;
  const int wid  = tid >> 6;
  const int wm   = wid >> 2;      // 0..1 : M
  const int wn   = wid & 3;       // 0..3 : N
  const int lrow = lane & 15;
  const int lk   = lane >> 4;     // 0..3
  const int slot = lk ^ ((lrow >> 1) & 3);   // conflict-free swizzle slot

  // A addressing: block-uniform base + per-lane 32-bit element offsets
  const float* abase = x + (size_t)row0 * KF;
  int aoff[4];
  #pragma unroll
  for (int m = 0; m < 4; ++m) {
    int r = min(wm * 64 + m * 16 + lrow, mrows - 1);   // clamp; stores guarded
    aoff[m] = r * KF + lk * 8;
  }

  // 2-deep A prefetch; parity index is static under full unroll (rule #20)
  f32x4 areg[2][4][2];
  auto issueA = [&](int kt, int sl) {
    #pragma unroll
    for (int m = 0; m < 4; ++m) {
      const float* p = abase + aoff[m] + kt * BK;
      areg[sl][m][0] = *(const f32x4*)(p);
      areg[sl][m][1] = *(const f32x4*)(p + 4);
    }
  };

  auto issueB = [&](int kt, int buf) {
    const unsigned short* sb = wimg + (((size_t)(g * 8 + kt)) << 13);  // 8192 ushorts
    #pragma unroll
    for (int r = 0; r < 2; ++r) {
      int c = wid * 2 + r;                           // 16 x 1KB chunks
      __builtin_amdgcn_global_load_lds(
          (const __attribute__((address_space(1))) void*)(sb + c * 512 + lane * 8),
          (__attribute__((address_space(3))) void*)((char*)&Bs[buf][0] + c * 1024),
          16, 0, 0);
    }
  };

  // acc[n][m]: o = wn*64 + n*16 + lk*4 + j ; xrow = wm*64 + m*16 + lrow
  f32x4 acc[4][4];
  #pragma unroll
  for (int n = 0; n < 4; ++n) {
    f32x4 b4 = *(const f32x4*)&bias[g * OF + wn * 64 + n * 16 + lk * 4];
    #pragma unroll
    for (int m = 0; m < 4; ++m) acc[n][m] = b4;
  }

  auto cvtA = [&](int sl, int m) -> bf16x8 {
    f32x4 lo = areg[sl][m][0], hi = areg[sl][m][1];
    u16x8 r;
    r[0]=f2bf(lo[0]); r[1]=f2bf(lo[1]); r[2]=f2bf(lo[2]); r[3]=f2bf(lo[3]);
    r[4]=f2bf(hi[0]); r[5]=f2bf(hi[1]); r[6]=f2bf(hi[2]); r[7]=f2bf(hi[3]);
    return __builtin_bit_cast(bf16x8, r);
  };

  auto compute = [&](const bf16x8* xf, int buf) {
    #pragma unroll
    for (int n = 0; n < 4; ++n) {
      int o16 = (wn * 64 + n * 16 + lrow) * 32 + slot * 8;
      bf16x8 wf = *(const bf16x8*)&Bs[buf][o16];
      #pragma unroll
      for (int m = 0; m < 4; ++m)
        acc[n][m] = __builtin_amdgcn_mfma_f32_16x16x32_bf16(wf, xf[m], acc[n][m], 0, 0, 0);
    }
  };

  if (PRECONV) {
    // Prologue keeps B(kt) strictly OLDER than A(kt) in the vmcnt FIFO.
    issueB(0, 0);
    issueA(0, 0);
    issueB(1, 1);
    issueA(1, 1);
    #pragma unroll
    for (int kt = 0; kt < NKT; ++kt) {
      // At top of iter kt, in flight: B(kt):2, A(kt):8, B(kt+1):2, A(kt+1):8.
      // Drain exactly B(kt) -> keep 18 (8 on the final iter).
      if (kt + 1 < NKT) asm volatile("s_waitcnt vmcnt(18)" ::: "memory");
      else              asm volatile("s_waitcnt vmcnt(8)"  ::: "memory");
      __builtin_amdgcn_s_barrier();
      __builtin_amdgcn_sched_barrier(0);
      if (kt + 2 < NKT) issueB(kt + 2, (kt + 2) % 3);
      bf16x8 xf[4];
      #pragma unroll
      for (int m = 0; m < 4; ++m) xf[m] = cvtA(kt & 1, m);  // waits A(kt); leaves
                                                            // B/A(kt+1),B(kt+2) in flight
      if (kt + 2 < NKT) issueA(kt + 2, kt & 1);             // refill freed slot
      __builtin_amdgcn_sched_barrier(0);
      compute(xf, kt % 3);
    }
  } else {
    // fallback: stage B from f32 weights each kt, single buffer
    #pragma unroll
    for (int kt = 0; kt < NKT; ++kt) {
      u16x8 v[2];
      #pragma unroll
      for (int r = 0; r < 2; ++r) {
        int sl = tid * 2 + r;          // slot16 index = o*4 + s'
        int o = sl >> 2, sp = sl & 3;
        int s = sp ^ ((o >> 1) & 3);
        const float* src = wf32 + ((size_t)(g * 256 + o) * 256 + kt * 32 + s * 8);
        f32x4 a = *(const f32x4*)src;
        f32x4 b = *(const f32x4*)(src + 4);
        v[r][0]=f2bf(a[0]); v[r][1]=f2bf(a[1]); v[r][2]=f2bf(a[2]); v[r][3]=f2bf(a[3]);
        v[r][4]=f2bf(b[0]); v[r][5]=f2bf(b[1]); v[r][6]=f2bf(b[2]); v[r][7]=f2bf(b[3]);
      }
      __syncthreads();
      #pragma unroll
      for (int r = 0; r < 2; ++r)
        *(u16x8*)&Bs[0][(tid * 2 + r) * 8] = v[r];
      __syncthreads();
      issueA(kt, 0);
      bf16x8 xf[4];
      #pragma unroll
      for (int m = 0; m < 4; ++m) xf[m] = cvtA(0, m);
      compute(xf, 0);
    }
  }

  // epilogue: pure f32x4 stores (bias already in acc)
  #pragma unroll
  for (int m = 0; m < 4; ++m) {
    int r = wm * 64 + m * 16 + lrow;
    if (r < mrows) {
      float* orow = out + (size_t)(row0 + r) * OF + wn * 64 + lk * 4;
      #pragma unroll
      for (int n = 0; n < 4; ++n)
        *(f32x4*)&orow[n * 16] = acc[n][m];
    }
  }
}

extern "C" void kernel_launch(void* const* d_in, const int* in_sizes, int n_in,
                              void* d_out, int out_size, void* d_ws, size_t ws_size,
                              hipStream_t stream) {
  const float* weight = (const float*)d_in[0];
  const float* bias   = (const float*)d_in[1];
  const float* x      = (const float*)d_in[2];
  const int*   counts = (const int*)d_in[3];
  float* out = (float*)d_out;

  int* offs = (int*)d_ws;
  unsigned short* wimg = (unsigned short*)((char*)d_ws + 4096);
  const size_t need = 4096 + (size_t)NG * 8 * 16384;  // ~32 MB image

  scan_kernel<<<1, 256, 0, stream>>>(counts, offs);

  if (ws_size >= need) {
    wconv_kernel<<<(NG * 8 * 256 * 4) / 512, 512, 0, stream>>>(weight, wimg);
    gemm_kernel<true><<<dim3(NTILES, NG), NTH, 0, stream>>>(x, weight, wimg, bias, offs, out);
  } else {
    gemm_kernel<false><<<dim3(NTILES, NG), NTH, 0, stream>>>(x, weight, wimg, bias, offs, out);
  }
}

// Round 8
// 277.238 us; speedup vs baseline: 2.6172x; 1.3976x over previous
//
#include <hip/hip_runtime.h>
#include <stdint.h>

#define NG 256      // num networks
#define KF 256      // IN_F
#define OF 256      // OUT_F
#define PAD 2048
#define RPB 256     // rows per block (2 sub-passes x 8 waves x 16 rows)
#define NTH 512     // 8 waves

using f32x4  = __attribute__((ext_vector_type(4))) float;
using bf16x8 = __attribute__((ext_vector_type(8))) __bf16;
using u16x8  = __attribute__((ext_vector_type(8))) unsigned short;

__device__ __forceinline__ unsigned short f2bf(float f) {
  unsigned u = __builtin_bit_cast(unsigned, f);
  u += 0x7fffu + ((u >> 16) & 1u);   // round-to-nearest-even
  return (unsigned short)(u >> 16);
}

// ---------------- offsets scan (1 block, 256 threads) ----------------
__global__ void scan_kernel(const int* __restrict__ counts, int* __restrict__ offs) {
  __shared__ int s[NG];
  int t = threadIdx.x;
  s[t] = counts[t];
  __syncthreads();
  #pragma unroll
  for (int d = 1; d < NG; d <<= 1) {
    int u = (t >= d) ? s[t - d] : 0;
    __syncthreads();
    s[t] += u;
    __syncthreads();
  }
  if (t == 0) offs[0] = 0;
  offs[t + 1] = s[t];
}

// ---------------- W f32 -> bf16 pre-swizzled image ----------------
// slot16 index = ((g*8+kt)*256 + o)*4 + s'   (16 B each)
// holds W[g][o][kt*32 + (s'^((o>>1)&3))*8 .. +8] as bf16x8.
// Linear global_load_lds reproduces the swizzled LDS tile (whole group = 128KB).
__global__ __launch_bounds__(512)
void wconv_kernel(const float* __restrict__ w, unsigned short* __restrict__ img) {
  int tid = blockIdx.x * 512 + threadIdx.x;   // one 16B slot each, 2^21 total
  int sp = tid & 3;
  int o  = (tid >> 2) & 255;
  int kt = (tid >> 10) & 7;
  int g  = tid >> 13;
  int s  = sp ^ ((o >> 1) & 3);
  int k0 = kt * 32 + s * 8;
  const float* src = w + ((size_t)(g * 256 + o) * 256 + k0);
  f32x4 a = *(const f32x4*)src;
  f32x4 b = *(const f32x4*)(src + 4);
  u16x8 r;
  r[0]=f2bf(a[0]); r[1]=f2bf(a[1]); r[2]=f2bf(a[2]); r[3]=f2bf(a[3]);
  r[4]=f2bf(b[0]); r[5]=f2bf(b[1]); r[6]=f2bf(b[2]); r[7]=f2bf(b[3]);
  *(u16x8*)(img + (size_t)tid * 8) = r;
}

// ---------------- grouped GEMM: full-W-in-LDS, barrier-free main loop ----------
// Block: 256 rows x 256 cols of one group. Stage whole W (128KB bf16) into LDS
// once, ONE barrier, then 8 waves free-run. R7 RACE LESSON: __syncthreads does
// NOT reliably publish global_load_lds DMA (vmcnt-tracked, no global writes to
// force a drain) -> wave W read wave V's region before V's DMA landed, only
// under hot-replay timing. Fix: pinned FIFO + explicit s_waitcnt vmcnt(16)
// (drains all 16 DMA loads, keeps 16 A-loads in flight) + raw s_barrier.
template<bool PRECONV>
__global__ __launch_bounds__(NTH, 2)
void gemm_kernel(const float* __restrict__ x,
                 const float* __restrict__ wf32,
                 const unsigned short* __restrict__ wimg,
                 const float* __restrict__ bias,
                 const int* __restrict__ offs,
                 float* __restrict__ out)
{
  __shared__ __align__(16) unsigned short Ws[8 * 8192];   // 128 KB: full W image

  const int g      = blockIdx.y;
  const int r0     = offs[g];
  const int cnt    = offs[g + 1] - r0;
  const int tstart = blockIdx.x * RPB;
  if (tstart >= cnt) return;
  const int mrows = min(RPB, cnt - tstart);
  const int row0  = r0 + tstart;

  const int tid  = threadIdx.x;
  const int lane = tid & 63;
  const int w    = tid >> 6;       // wave 0..7
  const int lrow = lane & 15;
  const int lk   = lane >> 4;      // 0..3
  const int slot = lk ^ ((lrow >> 1) & 3);   // conflict-free swizzle (verified: 0 conflicts)

  // ---- stage W into LDS ----
  if (PRECONV) {
    const char* src = (const char*)wimg + ((size_t)g << 17);
    #pragma unroll
    for (int i = 0; i < 16; ++i) {
      int base = i * 8192 + w * 1024;          // wave-uniform; HW adds lane*16
      __builtin_amdgcn_global_load_lds(
          (const __attribute__((address_space(1))) void*)(src + base + lane * 16),
          (__attribute__((address_space(3))) void*)((char*)Ws + base),
          16, 0, 0);
    }
  } else {
    #pragma unroll
    for (int i = 0; i < 16; ++i) {
      int sl = i * 512 + tid;                 // slot16 within group image
      int kt = sl >> 10, o = (sl >> 2) & 255, sp = sl & 3;
      int s  = sp ^ ((o >> 1) & 3);
      const float* p = wf32 + (size_t)(g * 256 + o) * 256 + kt * 32 + s * 8;
      f32x4 a = *(const f32x4*)p;
      f32x4 b = *(const f32x4*)(p + 4);
      u16x8 r;
      r[0]=f2bf(a[0]); r[1]=f2bf(a[1]); r[2]=f2bf(a[2]); r[3]=f2bf(a[3]);
      r[4]=f2bf(b[0]); r[5]=f2bf(b[1]); r[6]=f2bf(b[2]); r[7]=f2bf(b[3]);
      *(u16x8*)((char*)Ws + (size_t)sl * 16) = r;
    }
  }

  // ---- issue sub0 A loads AFTER the DMA issues (pinned), land under staging ----
  __builtin_amdgcn_sched_barrier(0);   // FIFO: all 16 gload_lds strictly first
  const int arow0 = min(w * 16 + lrow, mrows - 1);
  const float* ap0 = x + (size_t)(row0 + arow0) * KF + lk * 8;
  f32x4 af[16];
  #pragma unroll
  for (int kt = 0; kt < 8; ++kt) {
    af[kt * 2]     = *(const f32x4*)(ap0 + kt * 32);
    af[kt * 2 + 1] = *(const f32x4*)(ap0 + kt * 32 + 4);
  }
  __builtin_amdgcn_sched_barrier(0);   // FIFO: 16 A-loads strictly after

  if (PRECONV) {
    // Drain exactly the 16 gload_lds (A-loads stay in flight), then barrier.
    asm volatile("s_waitcnt vmcnt(16)" ::: "memory");
    __builtin_amdgcn_s_barrier();
    __builtin_amdgcn_sched_barrier(0); // no ds_read may hoist above the barrier
  } else {
    __syncthreads();                   // ds_write staging: lgkm handled here
  }

  const float* bp = bias + g * OF + lk * 4;

  #pragma unroll
  for (int sub = 0; sub < 2; ++sub) {
    const int rowbase = sub * 128 + w * 16;
    if (rowbase >= mrows) continue;          // wave-uniform

    if (sub == 1) {                          // sub0 preloaded above
      const int arow = min(rowbase + lrow, mrows - 1);
      const float* ap = x + (size_t)(row0 + arow) * KF + lk * 8;
      #pragma unroll
      for (int kt = 0; kt < 8; ++kt) {
        af[kt * 2]     = *(const f32x4*)(ap + kt * 32);
        af[kt * 2 + 1] = *(const f32x4*)(ap + kt * 32 + 4);
      }
    }

    // cvt A to bf16 frags (af dies here -> register peak stays low)
    bf16x8 xf[8];
    #pragma unroll
    for (int kt = 0; kt < 8; ++kt) {
      f32x4 lo = af[kt * 2], hi = af[kt * 2 + 1];
      u16x8 r;
      r[0]=f2bf(lo[0]); r[1]=f2bf(lo[1]); r[2]=f2bf(lo[2]); r[3]=f2bf(lo[3]);
      r[4]=f2bf(hi[0]); r[5]=f2bf(hi[1]); r[6]=f2bf(hi[2]); r[7]=f2bf(hi[3]);
      xf[kt] = __builtin_bit_cast(bf16x8, r);
    }

    // acc init with bias (D layout: lane holds out row=lrow, cols n*16+lk*4+j)
    f32x4 acc[16];
    #pragma unroll
    for (int n = 0; n < 16; ++n) acc[n] = *(const f32x4*)(bp + n * 16);

    // main compute: 128 ds_read_b128 + 128 MFMA, no barriers
    #pragma unroll
    for (int kt = 0; kt < 8; ++kt) {
      #pragma unroll
      for (int n = 0; n < 16; ++n) {
        bf16x8 wf = *(const bf16x8*)&Ws[kt * 8192 + ((n * 16 + lrow) * 4 + slot) * 8];
        acc[n] = __builtin_amdgcn_mfma_f32_16x16x32_bf16(wf, xf[kt], acc[n], 0, 0, 0);
      }
    }

    // store
    const int r = rowbase + lrow;
    if (r < mrows) {
      float* orow = out + (size_t)(row0 + r) * OF + lk * 4;
      #pragma unroll
      for (int n = 0; n < 16; ++n)
        *(f32x4*)&orow[n * 16] = acc[n];
    }
  }
}

extern "C" void kernel_launch(void* const* d_in, const int* in_sizes, int n_in,
                              void* d_out, int out_size, void* d_ws, size_t ws_size,
                              hipStream_t stream) {
  const float* weight = (const float*)d_in[0];
  const float* bias   = (const float*)d_in[1];
  const float* x      = (const float*)d_in[2];
  const int*   counts = (const int*)d_in[3];
  float* out = (float*)d_out;

  int* offs = (int*)d_ws;
  unsigned short* wimg = (unsigned short*)((char*)d_ws + 4096);
  const size_t need = 4096 + (size_t)NG * 8 * 16384;  // ~32 MB image

  scan_kernel<<<1, 256, 0, stream>>>(counts, offs);

  if (ws_size >= need) {
    wconv_kernel<<<(NG * 8 * 256 * 4) / 512, 512, 0, stream>>>(weight, wimg);
    gemm_kernel<true><<<dim3(PAD / RPB, NG), NTH, 0, stream>>>(x, weight, wimg, bias, offs, out);
  } else {
    gemm_kernel<false><<<dim3(PAD / RPB, NG), NTH, 0, stream>>>(x, weight, wimg, bias, offs, out);
  }
}